// Round 7
// baseline (119.280 us; speedup 1.0000x reference)
//
#include <hip/hip_runtime.h>
#include <math.h>

#define NV 512
#define KC 32
#define NB 192
#define LOG2PI 1.8378770664093453f
#define MAGIC 0x3C96A55A

typedef __attribute__((ext_vector_type(8))) short short8;
typedef __attribute__((ext_vector_type(4))) float float4v;

// ws float offsets — every region is either per-block EXCLUSIVE (overwritten
// each launch) or guarded by MAGIC value-flags; nothing needs zero-init,
// harness 0xAA poison is harmless.
#define WS_PM    0        // [96][512] per-bid partial sm tile (r*32+c)
#define WS_VP    49152    // [96][64]  per-bid column sums (i-tile local)
#define WS_MMV   55296    // [96]      per-bid sum of mean^2
#define WS_ST    55392    // [12][580] stats: u 512, sx1 32, sx2 32, xx 1
#define ST_STRIDE 580
#define WS_SMP   62352    // [12][64]  leader out: SM1[32], SM2[32] per b-tile
#define WS_P     63120    // coef 32, logdet 1
// int offsets (flags)
#define WS_WFLAG 63160    // [96] W-convert strips  (g*12 + j)
#define WS_XFLAG 63256    // [96] X-convert strips  (h*8 + t)
#define WS_DONE  63352    // [96] per-bid gemm partials written
#define WS_L2F   63448    // [12] per-b-tile leader reduction done
// bf16 regions (16B aligned: offset*4 % 16 == 0)
#define WS_XBF   63464    // X bf16 [192*512] shorts
#define WS_WBF   112616   // W-masked bf16 [512*512] shorts

static __device__ inline ushort f2bf(float f) {
    const uint u = __float_as_uint(f);
    return (ushort)((u + 0x7fffu + ((u >> 16) & 1u)) >> 16);   // RNE
}
static __device__ inline void spin_eq(int* p) {
    while (__hip_atomic_load(p, __ATOMIC_ACQUIRE, __HIP_MEMORY_SCOPE_AGENT) != MAGIC) {}
}
static __device__ inline void flag_set(int* p) {
    __hip_atomic_store(p, MAGIC, __ATOMIC_RELEASE, __HIP_MEMORY_SCOPE_AGENT);
}

__global__ __launch_bounds__(256) void mono_kernel(
    const float* __restrict__ X, const float* __restrict__ C,
    const float* __restrict__ G, const float* __restrict__ W,
    const float* __restrict__ bias, const float* __restrict__ sigma,
    const float* __restrict__ rho, float* __restrict__ wsF,
    int* __restrict__ wsI, float* __restrict__ out)
{
    const int bid = blockIdx.x, tid = threadIdx.x;
    const int blk_b = bid >> 3, blk_i = bid & 7;   // 12 b-tiles x 8 i-tiles
    const int b0 = blk_b * 16, i0 = blk_i * 64;
    const int w = tid >> 6, lane = tid & 63;
    const int m = lane & 15, q = lane >> 4;
    const int i0w = i0 + w * 16;

    __shared__ int asg[NV];
    __shared__ float Gs[KC * KC];
    __shared__ float smL[16 * KC];
    __shared__ float varr[64];
    __shared__ float mmred[4];
    __shared__ float smrows[16][KC];
    __shared__ int cnt[KC];
    __shared__ float ldred[KC];
    __shared__ float SM1L[KC], SM2L[KC];
    __shared__ float SM1s[KC], SM2s[KC];
    __shared__ float accs[4];

    // ---- 1. preamble: asg from one-hot C, Gs, zero local accumulators
    {
        const int n0 = tid * 2;
        #pragma unroll
        for (int hh = 0; hh < 2; ++hh) {
            const int n = n0 + hh;
            const float* row = C + n * KC;
            float a = 0.f;
            #pragma unroll
            for (int c4 = 0; c4 < 8; ++c4) {
                const float4 f = *(const float4*)(row + c4 * 4);
                a += f.x * (float)(c4 * 4) + f.y * (float)(c4 * 4 + 1)
                   + f.z * (float)(c4 * 4 + 2) + f.w * (float)(c4 * 4 + 3);
            }
            asg[n] = (int)(a + 0.5f);
        }
    }
    for (int l = tid; l < KC * KC; l += 256) Gs[l] = G[l];
    for (int l = tid; l < 16 * KC; l += 256) smL[l] = 0.f;
    if (tid < 64) varr[tid] = 0.f;
    __syncthreads();

    // ---- 2a. convert masked W strip: rows i0 + blk_b*6 .. (<=6 rows)
    {
        const int r0 = blk_b * 6;
        const int nrows = min(6, 64 - r0) > 0 ? min(6, 64 - r0) : 0;
        if (nrows > 0) {
            ushort* wbf = (ushort*)(wsF + WS_WBF);
            const int tot = nrows * NV;
            for (int l = tid * 4; l < tot; l += 1024) {
                const int ir = i0 + r0 + (l >> 9), k = l & 511;
                const float* grow = Gs + asg[ir] * KC;
                const float4 f = *(const float4*)(W + ir * NV + k);
                ushort4 o;
                o.x = f2bf(f.x * grow[asg[k]]);
                o.y = f2bf(f.y * grow[asg[k + 1]]);
                o.z = f2bf(f.z * grow[asg[k + 2]]);
                o.w = f2bf(f.w * grow[asg[k + 3]]);
                *(ushort4*)(wbf + ir * NV + k) = o;
            }
        }
    }
    // ---- 2b. convert X strip: rows b0 + blk_i*2, +2
    {
        ushort* xbf = (ushort*)(wsF + WS_XBF);
        const int row = b0 + blk_i * 2 + (tid >> 7);
        const int k = (tid & 127) * 4;
        const float4 f = *(const float4*)(X + row * NV + k);
        ushort4 o;
        o.x = f2bf(f.x); o.y = f2bf(f.y); o.z = f2bf(f.z); o.w = f2bf(f.w);
        *(ushort4*)(xbf + row * NV + k) = o;
    }
    // ---- 3. publish converts
    __syncthreads();
    if (tid == 0) {
        __threadfence();
        flag_set(&wsI[WS_WFLAG + blk_i * 12 + blk_b]);
        flag_set(&wsI[WS_XFLAG + blk_b * 8 + blk_i]);
    }

    // ---- 4a. X stats (exact fp32), blk_i==1 blocks, rows [b0, b0+16)
    if (blk_i == 1) {
        for (int l = tid; l < 16 * KC; l += 256) ((float*)smrows)[l] = 0.f;
        if (tid < 4) mmred[tid] = 0.f;
        __syncthreads();
        const int c0 = tid * 2;
        const int ca = asg[c0], cb = asg[c0 + 1];
        float u0 = 0.f, u1 = 0.f, xx = 0.f;
        #pragma unroll
        for (int r = 0; r < 16; ++r) {
            const float2 xv = *(const float2*)(X + (b0 + r) * NV + c0);
            u0 += xv.x; u1 += xv.y;
            xx += xv.x * xv.x + xv.y * xv.y;
            atomicAdd(&smrows[r][ca], xv.x);
            atomicAdd(&smrows[r][cb], xv.y);
        }
        for (int off = 32; off; off >>= 1) xx += __shfl_down(xx, off, 64);
        if ((tid & 63) == 0) mmred[tid >> 6] = xx;
        __syncthreads();
        float* st = wsF + WS_ST + blk_b * ST_STRIDE;
        st[c0] = u0; st[c0 + 1] = u1;
        if (tid < KC) {
            float s1 = 0.f, s2 = 0.f;
            #pragma unroll
            for (int r = 0; r < 16; ++r) { const float s = smrows[r][tid]; s1 += s; s2 += s * s; }
            st[512 + tid] = s1;
            st[544 + tid] = s2;
        }
        if (tid == 0) st[576] = mmred[0] + mmred[1] + mmred[2] + mmred[3];
        __syncthreads();
    }
    // ---- 4b. coef/logdet, block 0
    if (bid == 0) {
        if (tid < KC) cnt[tid] = 0;
        __syncthreads();
        for (int n = tid; n < NV; n += 256) atomicAdd(&cnt[asg[n]], 1);
        __syncthreads();
        const float s2v = sigma[0] * sigma[0], rh = rho[0];
        const float av = s2v * (1.f - rh), bv = s2v * rh;
        if (tid < KC) {
            const int nc = cnt[tid];
            wsF[WS_P + tid] = bv / (av * (av + bv * (float)nc));
            ldred[tid] = (float)(nc - 1) * logf(av) + logf(av + bv * (float)nc);
        }
        __syncthreads();
        if (tid == 0) {
            float ld = 0.f;
            for (int c2 = 0; c2 < KC; ++c2) ld += ldred[c2];
            wsF[WS_P + 32] = ld;
        }
        __syncthreads();
    }

    // ---- 5. spin for this block's converted inputs (wave-gated)
    if (lane < 12)      spin_eq(&wsI[WS_WFLAG + blk_i * 12 + lane]);
    else if (lane < 20) spin_eq(&wsI[WS_XFLAG + blk_b * 8 + (lane - 12)]);
    __threadfence();   // acquire: invalidate stale lines before fragment reads

    // ---- 6. MFMA GEMM, fragments direct from global bf16
    const ushort* xbf = (const ushort*)(wsF + WS_XBF);
    const ushort* wbf = (const ushort*)(wsF + WS_WBF);
    const short8* ap = (const short8*)(xbf + (b0 + m) * NV + q * 8);
    const short8* bp = (const short8*)(wbf + (i0w + m) * NV + q * 8);
    float4v acc = {0.f, 0.f, 0.f, 0.f};
    #pragma unroll
    for (int s = 0; s < 16; ++s) {
        const short8 a = ap[s * 4];
        const short8 b = bp[s * 4];
        acc = __builtin_amdgcn_mfma_f32_16x16x32_bf16(a, b, acc, 0, 0, 0);
    }

    // epilogue: C/D layout col=lane&15, row=q*4+reg (m89-verified)
    const int col = i0w + m;
    const float bv = bias[col];
    const int ca = asg[col];
    float vsum = 0.f, mml = 0.f;
    #pragma unroll
    for (int r = 0; r < 4; ++r) {
        const float val = acc[r] + bv;
        vsum += val; mml += val * val;
        atomicAdd(&smL[(q * 4 + r) * KC + ca], val);
    }
    atomicAdd(&varr[w * 16 + m], vsum);
    for (int off = 32; off; off >>= 1) mml += __shfl_down(mml, off, 64);
    if (lane == 0) mmred[w] = mml;
    __syncthreads();

    // ---- 7. write exclusive partials, publish DONE
    {
        float* pdst = wsF + WS_PM + bid * 512;
        for (int l = tid; l < 512; l += 256) pdst[l] = smL[l];
        if (tid < 64) wsF[WS_VP + bid * 64 + tid] = varr[tid];
        if (tid == 0) wsF[WS_MMV + bid] = mmred[0] + mmred[1] + mmred[2] + mmred[3];
    }
    __syncthreads();
    if (tid == 0) {
        __threadfence();
        flag_set(&wsI[WS_DONE + bid]);
    }

    // ---- 8. b-tile leader (blk_i==0): reduce 8 sibling tiles -> SM1/SM2
    if (blk_i == 0) {
        if (lane < 8) spin_eq(&wsI[WS_DONE + blk_b * 8 + lane]);
        __threadfence();
        if (tid < KC) { SM1L[tid] = 0.f; SM2L[tid] = 0.f; }
        __syncthreads();
        const int c = tid & 31;
        for (int rr = tid >> 5; rr < 16; rr += 8) {
            float s = 0.f;
            #pragma unroll
            for (int t = 0; t < 8; ++t)
                s += wsF[WS_PM + (blk_b * 8 + t) * 512 + rr * KC + c];
            atomicAdd(&SM1L[c], s);
            atomicAdd(&SM2L[c], s * s);
        }
        __syncthreads();
        if (tid < KC) {
            wsF[WS_SMP + blk_b * 64 + tid] = SM1L[tid];
            wsF[WS_SMP + blk_b * 64 + 32 + tid] = SM2L[tid];
        }
        __syncthreads();
        if (tid == 0) { __threadfence(); flag_set(&wsI[WS_L2F + blk_b]); }
    }

    // ---- 9. finalizer (bid==95): combine everything -> out[0]
    if (bid == 95) {
        if (tid < 96)       spin_eq(&wsI[WS_DONE + tid]);
        else if (tid < 108) spin_eq(&wsI[WS_L2F + tid - 96]);
        __syncthreads();
        __threadfence();
        const float* st = wsF + WS_ST;
        if (tid < KC) {
            float a1 = 0.f, a2 = 0.f;
            #pragma unroll
            for (int h2 = 0; h2 < 12; ++h2) {
                a1 += wsF[WS_SMP + h2 * 64 + tid];
                a2 += wsF[WS_SMP + h2 * 64 + 32 + tid];
            }
            SM1s[tid] = a1; SM2s[tid] = a2;
        }
        if (tid < 4) accs[tid] = 0.f;
        __syncthreads();
        {   // cross term u.v, 2 cols per thread
            float cr = 0.f;
            #pragma unroll
            for (int hh = 0; hh < 2; ++hh) {
                const int i = tid + hh * 256;
                float u = 0.f;
                #pragma unroll
                for (int sb = 0; sb < 12; ++sb) u += st[sb * ST_STRIDE + i];
                const int g2 = i >> 6, loc = i & 63;
                float v = 0.f;
                #pragma unroll
                for (int h2 = 0; h2 < 12; ++h2) v += wsF[WS_VP + (h2 * 8 + g2) * 64 + loc];
                cr += u * v;
            }
            for (int off = 32; off; off >>= 1) cr += __shfl_down(cr, off, 64);
            if ((tid & 63) == 0) atomicAdd(&accs[2], cr);
        }
        {   // MM
            float mm = (tid < 96) ? wsF[WS_MMV + tid] : 0.f;
            for (int off = 32; off; off >>= 1) mm += __shfl_down(mm, off, 64);
            if ((tid & 63) == 0) atomicAdd(&accs[0], mm);
        }
        {   // XX
            float xx = (tid < 12) ? st[tid * ST_STRIDE + 576] : 0.f;
            for (int off = 32; off; off >>= 1) xx += __shfl_down(xx, off, 64);
            if ((tid & 63) == 0) atomicAdd(&accs[1], xx);
        }
        __syncthreads();
        {   // Q term
            float qv = 0.f;
            if (tid < KC) {
                float s1 = 0.f, s2 = 0.f;
                #pragma unroll
                for (int sb = 0; sb < 12; ++sb) {
                    s1 += st[sb * ST_STRIDE + 512 + tid];
                    s2 += st[sb * ST_STRIDE + 544 + tid];
                }
                const float coef = wsF[WS_P + tid];
                qv = coef * (s2 * (1.f / NB) + SM2s[tid] * (1.f / NB)
                             - 2.f * s1 * SM1s[tid] * (1.f / ((float)NB * (float)NB)));
            }
            for (int off = 32; off; off >>= 1) qv += __shfl_down(qv, off, 64);
            if (tid == 0) atomicAdd(&accs[3], qv);
        }
        __syncthreads();
        if (tid == 0) {
            const float s2v = sigma[0] * sigma[0], rh = rho[0];
            const float av = s2v * (1.f - rh);
            const float meanD2 = accs[1] * (1.f / NB) + accs[0] * (1.f / NB)
                               - 2.f * accs[2] / ((float)NB * (float)NB);
            const float maha = meanD2 / av - accs[3];
            out[0] = -0.5f * (maha + wsF[WS_P + 32] + (float)NV * LOG2PI);
        }
    }
}

extern "C" void kernel_launch(void* const* d_in, const int* in_sizes, int n_in,
                              void* d_out, int out_size, void* d_ws, size_t ws_size,
                              hipStream_t stream) {
    const float* X     = (const float*)d_in[0];
    const float* C     = (const float*)d_in[1];
    const float* G     = (const float*)d_in[2];
    const float* W     = (const float*)d_in[3];
    const float* b     = (const float*)d_in[4];
    const float* sigma = (const float*)d_in[5];
    const float* rho   = (const float*)d_in[6];
    float* wsF = (float*)d_ws;
    int*   wsI = (int*)d_ws;
    float* out = (float*)d_out;

    hipLaunchKernelGGL(mono_kernel, dim3(96), dim3(256), 0, stream,
                       X, C, G, W, b, sigma, rho, wsF, wsI, out);
}

// Round 8
// 87.645 us; speedup vs baseline: 1.3609x; 1.3609x over previous
//
#include <hip/hip_runtime.h>
#include <math.h>

#define NV 512
#define KC 32
#define NB 192
#define LOG2PI 1.8378770664093453f

typedef __attribute__((ext_vector_type(8))) short short8;
typedef __attribute__((ext_vector_type(4))) float float4v;

// ws layout (float units):
#define WS_SM    0        // sm[192*32]: zeroed by prep (node1), atomic-accum by gemm (node2)
#define WS_GV    6144     // 96 slices x 65: [v 64][mm 1]
#define WS_STATS 12400    // 24 slices x 608: [u 512][sx1 32][sx2 32][xx 1]
#define WS_P     27000    // [coef 32][logdet 1]
#define WS_ASG   27040    // int asg[512]
#define WS_CNT   27552    // int completion counter (zeroed by prep)
#define WS_XBF   27556    // bf16 X [192*512]  (16B-aligned: 27556*4 % 16 == 0)
#define WS_WBF   76708    // bf16 Wm [512*512] (16B-aligned)

static __device__ inline ushort f2bf(float f) {
    uint u = __float_as_uint(f);
    uint r = (u + 0x7fffu + ((u >> 16) & 1u)) >> 16;   // RNE
    return (ushort)r;
}

// ---------------- node 1: convert + stats + prep ----------------
__global__ __launch_bounds__(256) void prep_kernel(
    const float* __restrict__ X, const float* __restrict__ C,
    const float* __restrict__ G, const float* __restrict__ W,
    const float* __restrict__ bias, const float* __restrict__ sigma,
    const float* __restrict__ rho, float* __restrict__ wsF, int* __restrict__ wsI)
{
    const int bid = blockIdx.x, tid = threadIdx.x;
    __shared__ int asg[NV];
    __shared__ float Gs[KC * KC];
    __shared__ float smrows[8][KC];
    __shared__ float redw[4];

    // cluster assignment from one-hot C (exact 0/1 values)
    for (int n = tid; n < NV; n += 256) {
        const float* row = C + n * KC;
        float a = 0.f;
        #pragma unroll
        for (int c2 = 0; c2 < KC; ++c2) a += row[c2] * (float)c2;
        asg[n] = (int)(a + 0.5f);
    }

    if (bid < 24) {
        // ---- convert X rows [bid*8, +8) to bf16
        __syncthreads();
        ushort* xbf = (ushort*)(wsF + WS_XBF);
        const int base = bid * 8 * NV;
        #pragma unroll
        for (int p = 0; p < 4; ++p) {
            const int off = base + tid * 4 + p * 1024;
            const float4 f = *(const float4*)(X + off);
            ushort4 o;
            o.x = f2bf(f.x); o.y = f2bf(f.y); o.z = f2bf(f.z); o.w = f2bf(f.w);
            *(ushort4*)(xbf + off) = o;
        }
    } else if (bid < 88) {
        // ---- convert masked W rows [(bid-24)*8, +8) to bf16
        for (int l = tid; l < KC * KC; l += 256) Gs[l] = G[l];
        __syncthreads();
        ushort* wbf = (ushort*)(wsF + WS_WBF);
        const int i0 = (bid - 24) * 8;
        #pragma unroll
        for (int p = 0; p < 4; ++p) {
            const int l = tid * 4 + p * 1024;          // 0..4095 strip-local
            const int ir = i0 + (l >> 9), k = l & 511;
            const float* grow = Gs + asg[ir] * KC;
            const float4 f = *(const float4*)(W + ir * NV + k);
            ushort4 o;
            o.x = f2bf(f.x * grow[asg[k]]);
            o.y = f2bf(f.y * grow[asg[k + 1]]);
            o.z = f2bf(f.z * grow[asg[k + 2]]);
            o.w = f2bf(f.w * grow[asg[k + 3]]);
            *(ushort4*)(wbf + ir * NV + k) = o;
        }
    } else if (bid < 112) {
        // ---- X stats: 8 rows -> u partials, xx, per-row cluster sums -> sx1/sx2
        for (int l = tid; l < 8 * KC; l += 256) ((float*)smrows)[l] = 0.f;
        if (tid < 4) redw[tid] = 0.f;
        __syncthreads();
        const int sb = bid - 88, row0 = sb * 8;
        const int c0 = tid * 2;
        const int ca = asg[c0], cb = asg[c0 + 1];
        float u0 = 0.f, u1 = 0.f, xx = 0.f;
        #pragma unroll
        for (int r = 0; r < 8; ++r) {
            const float2 xv = *(const float2*)(X + (row0 + r) * NV + c0);
            u0 += xv.x; u1 += xv.y;
            xx += xv.x * xv.x + xv.y * xv.y;
            atomicAdd(&smrows[r][ca], xv.x);
            atomicAdd(&smrows[r][cb], xv.y);
        }
        for (int off = 32; off; off >>= 1) xx += __shfl_down(xx, off, 64);
        if ((tid & 63) == 0) redw[tid >> 6] = xx;
        __syncthreads();
        float* slice = wsF + WS_STATS + sb * 608;
        slice[c0] = u0; slice[c0 + 1] = u1;
        if (tid < KC) {
            float s1 = 0.f, s2 = 0.f;
            #pragma unroll
            for (int r = 0; r < 8; ++r) { const float s = smrows[r][tid]; s1 += s; s2 += s * s; }
            slice[512 + tid] = s1;
            slice[544 + tid] = s2;
        }
        if (tid == 0) slice[576] = redw[0] + redw[1] + redw[2] + redw[3];
    } else {
        // ---- prep: counts -> coef/logdet, persist asg, zero sm + counter
        __shared__ int cnt[KC];
        __shared__ float ldred[KC];
        if (tid < KC) cnt[tid] = 0;
        __syncthreads();
        for (int n = tid; n < NV; n += 256) {
            atomicAdd(&cnt[asg[n]], 1);
            wsI[WS_ASG + n] = asg[n];
        }
        for (int l = tid; l < NB * KC; l += 256) wsF[WS_SM + l] = 0.f;
        if (tid == 0) wsI[WS_CNT] = 0;
        __syncthreads();
        const float s2v = sigma[0] * sigma[0];
        const float rh = rho[0];
        const float av = s2v * (1.f - rh), bv = s2v * rh;
        if (tid < KC) {
            const int nc = cnt[tid];
            wsF[WS_P + tid] = bv / (av * (av + bv * (float)nc));
            ldred[tid] = (float)(nc - 1) * logf(av) + logf(av + bv * (float)nc);
        }
        __syncthreads();
        if (tid == 0) {
            float ld = 0.f;
            for (int c2 = 0; c2 < KC; ++c2) ld += ldred[c2];
            wsF[WS_P + 32] = ld;
        }
    }
}

// ---------------- node 2: MFMA GEMM + last-block finalize ----------------
__global__ __launch_bounds__(256) void gemm_kernel(
    const float* __restrict__ bias, const float* __restrict__ sigma,
    const float* __restrict__ rho, float* __restrict__ wsF,
    int* __restrict__ wsI, float* __restrict__ out)
{
    const int bid = blockIdx.x, tid = threadIdx.x;
    const int blk_b = bid >> 3, blk_i = bid & 7;     // 12 b-tiles x 8 i-tiles
    const int b0 = blk_b * 16, i0blk = blk_i * 64;
    const int w = tid >> 6, lane = tid & 63;
    const int m = lane & 15, q = lane >> 4;
    const int i0w = i0blk + w * 16;

    __shared__ float smL[16 * KC];
    __shared__ float varr[64];
    __shared__ int asgc[64];
    __shared__ float mmred[4];
    __shared__ int isLast;
    for (int l = tid; l < 16 * KC; l += 256) smL[l] = 0.f;
    if (tid < 64) { varr[tid] = 0.f; asgc[tid] = wsI[WS_ASG + i0blk + tid]; }
    if (tid < 4) mmred[tid] = 0.f;

    const ushort* xbf = (const ushort*)(wsF + WS_XBF);
    const ushort* wbf = (const ushort*)(wsF + WS_WBF);
    const short8* ap = (const short8*)(xbf + (b0 + m) * NV + q * 8);
    const short8* bp = (const short8*)(wbf + (i0w + m) * NV + q * 8);
    float4v acc = {0.f, 0.f, 0.f, 0.f};
    #pragma unroll
    for (int s = 0; s < 16; ++s) {
        const short8 a = ap[s * 4];     // s*32 shorts = 4 short8
        const short8 b = bp[s * 4];
        acc = __builtin_amdgcn_mfma_f32_16x16x32_bf16(a, b, acc, 0, 0, 0);
    }
    __syncthreads();

    // epilogue: C/D layout col=lane&15, row=q*4+reg (m89-verified)
    const int col = i0w + m;
    const float bv = bias[col];
    const int ca = asgc[w * 16 + m];
    float vsum = 0.f, mml = 0.f;
    #pragma unroll
    for (int r = 0; r < 4; ++r) {
        const float val = acc[r] + bv;
        vsum += val; mml += val * val;
        atomicAdd(&smL[(q * 4 + r) * KC + ca], val);
    }
    atomicAdd(&varr[w * 16 + m], vsum);
    for (int off = 32; off; off >>= 1) mml += __shfl_down(mml, off, 64);
    if (lane == 0) mmred[w] = mml;
    __syncthreads();

    float* smG = wsF + WS_SM;
    for (int l = tid; l < 16 * KC; l += 256)
        atomicAdd(&smG[(b0 + (l >> 5)) * KC + (l & 31)], smL[l]);
    float* slice = wsF + WS_GV + bid * 65;
    if (tid < 64) slice[tid] = varr[tid];
    if (tid == 0) slice[64] = mmred[0] + mmred[1] + mmred[2] + mmred[3];

    // ---- completion protocol: release writes, bump counter, last block finalizes
    __syncthreads();                 // all block stores/atomics drained (vmcnt 0)
    if (tid == 0) {
        __threadfence();             // agent-scope release: L2 writeback
        const int old = atomicAdd(&wsI[WS_CNT], 1);
        isLast = (old == 95);
    }
    __syncthreads();
    if (!isLast) return;
    if (tid == 0) __threadfence();   // acquire: invalidate stale lines before reads
    __syncthreads();

    // ---- finalize (R3 body): reads sm (atomics), gv slices, stats, coef
    __shared__ float SM1s[KC], SM2s[KC];
    __shared__ float accs[4];        // 0:MM 1:XX 2:cross(u.v) 3:Q
    if (tid < KC) { SM1s[tid] = 0.f; SM2s[tid] = 0.f; }
    if (tid < 4) accs[tid] = 0.f;
    __syncthreads();
    const float* sm = wsF + WS_SM;
    const float* gv = wsF + WS_GV;
    const float* st = wsF + WS_STATS;

    {   // SM1/SM2 over sm[192][32], coalesced in c
        const int c = tid & 31, r0 = tid >> 5;
        float s1 = 0.f, s2 = 0.f;
        #pragma unroll
        for (int j = 0; j < 24; ++j) {
            const float s = sm[(r0 + 8 * j) * KC + c];
            s1 += s; s2 += s * s;
        }
        atomicAdd(&SM1s[c], s1);
        atomicAdd(&SM2s[c], s2);
    }
    {   // u, v, cross term (2 cols per thread)
        float cr = 0.f;
        #pragma unroll
        for (int h = 0; h < 2; ++h) {
            const int i = tid + h * 256;
            float u = 0.f;
            #pragma unroll
            for (int sb = 0; sb < 24; ++sb) u += st[sb * 608 + i];
            float v = 0.f;
            const int bi2 = i >> 6, loc = i & 63;
            #pragma unroll
            for (int bb = 0; bb < 12; ++bb) v += gv[(bb * 8 + bi2) * 65 + loc];
            cr += u * v;
        }
        for (int off = 32; off; off >>= 1) cr += __shfl_down(cr, off, 64);
        if ((tid & 63) == 0) atomicAdd(&accs[2], cr);
    }
    {   // MM
        float mm = (tid < 96) ? gv[tid * 65 + 64] : 0.f;
        for (int off = 32; off; off >>= 1) mm += __shfl_down(mm, off, 64);
        if ((tid & 63) == 0) atomicAdd(&accs[0], mm);
    }
    {   // XX
        float xx = (tid < 24) ? st[tid * 608 + 576] : 0.f;
        for (int off = 32; off; off >>= 1) xx += __shfl_down(xx, off, 64);
        if ((tid & 63) == 0) atomicAdd(&accs[1], xx);
    }
    __syncthreads();
    {   // Q term
        float qv = 0.f;
        if (tid < KC) {
            float s1 = 0.f, s2 = 0.f;
            #pragma unroll
            for (int sb = 0; sb < 24; ++sb) {
                s1 += st[sb * 608 + 512 + tid];
                s2 += st[sb * 608 + 544 + tid];
            }
            const float coef = wsF[WS_P + tid];
            qv = coef * (s2 * (1.f / NB) + SM2s[tid] * (1.f / NB)
                         - 2.f * s1 * SM1s[tid] * (1.f / ((float)NB * (float)NB)));
        }
        for (int off = 32; off; off >>= 1) qv += __shfl_down(qv, off, 64);
        if (tid == 0) atomicAdd(&accs[3], qv);
    }
    __syncthreads();
    if (tid == 0) {
        const float s2v = sigma[0] * sigma[0];
        const float rh = rho[0];
        const float av = s2v * (1.f - rh);
        const float meanD2 = accs[1] * (1.f / NB) + accs[0] * (1.f / NB)
                           - 2.f * accs[2] / ((float)NB * (float)NB);
        const float maha = meanD2 / av - accs[3];
        out[0] = -0.5f * (maha + wsF[WS_P + 32] + (float)NV * LOG2PI);
    }
}

extern "C" void kernel_launch(void* const* d_in, const int* in_sizes, int n_in,
                              void* d_out, int out_size, void* d_ws, size_t ws_size,
                              hipStream_t stream) {
    const float* X     = (const float*)d_in[0];
    const float* C     = (const float*)d_in[1];
    const float* G     = (const float*)d_in[2];
    const float* W     = (const float*)d_in[3];
    const float* b     = (const float*)d_in[4];
    const float* sigma = (const float*)d_in[5];
    const float* rho   = (const float*)d_in[6];
    float* wsF = (float*)d_ws;
    int*   wsI = (int*)d_ws;
    float* out = (float*)d_out;

    hipLaunchKernelGGL(prep_kernel, dim3(113), dim3(256), 0, stream,
                       X, C, G, W, b, sigma, rho, wsF, wsI);
    hipLaunchKernelGGL(gemm_kernel, dim3(96), dim3(256), 0, stream,
                       b, sigma, rho, wsF, wsI, out);
}